// Round 14
// baseline (20.643 us; speedup 1.0000x reference)
//
#include <hip/hip_runtime.h>
#include <hip/hip_fp16.h>

#define BATCH  1024
#define NVARS  2048
#define N_OUT  4096

typedef float f32x4 __attribute__((ext_vector_type(4)));

__device__ __forceinline__ __half2 u2h2(unsigned u) {
    union { unsigned u; __half2 h; } c; c.u = u; return c.h;
}
__device__ __forceinline__ unsigned h22u(__half2 h) {
    union { unsigned u; __half2 h; } c; c.h = h; return c.u;
}
__device__ __forceinline__ void sel2sc(unsigned sel, unsigned& s, unsigned& c) {
    // half2 constants: 1.0h2 = 0x3C003C00, -1.0h2 = 0xBC00BC00
    c = (sel & 1u) ? 0x3C003C00u : 0u;
    s = (sel == 2u) ? 0x3C003C00u : (sel == 3u) ? 0xBC00BC00u : 0u;
}

// ---------------- single fused kernel ----------------
// 256 blocks x 1024 threads, 1 block/CU (144 KiB LDS). Block = (window w =
// 32 cols, chunk = 512 outputs); XCD k = bx&7 owns windows 4k..4k+3 so the
// 8 blocks sharing a window slice hit the same L2.
// Phase 0a: stage x slice (2048 rows x 32 f32 cols) -> LDS fp16 (128 KiB),
//           coalesced full-line reads, cvt in flight.
// Phase 0b: threads 0..511 walk the 4-level index tree for the block's 512
//           outputs -> Tl[o*8+m] packed pair-words (16 KiB LDS).
// Phase 1:  2 passes x 256 outputs: 16 ds_read_b128 leaf gathers + fp16 tree,
//           f32 top sum, full-line NT store pairs (R13-proven).
__global__ __launch_bounds__(1024) void knowledge_all(
    const float* __restrict__ x,
    const int2* __restrict__ idx0,
    const int2* __restrict__ idx1,
    const int2* __restrict__ idx2,
    const int2* __restrict__ idx3,
    float* __restrict__ out)
{
    __shared__ char     lds[131072];   // window: row r at byte r*64 (32 fp16)
    __shared__ unsigned Tl[512 * 8];   // packed pair-words for this chunk

    const int bx    = blockIdx.x;      // 256
    const int tid   = threadIdx.x;     // 0..1023
    const int xcd   = bx & 7;
    const int slot  = bx >> 3;         // 0..31
    const int w     = xcd * 4 + (slot & 3);  // window 0..31 (cols w*32..w*32+31)
    const int chunk = slot >> 2;       // 0..7 (512 outputs each)

    // ---- phase 0a: stage x slice -> LDS fp16 ----
    {
        const float* xw = x + w * 32;
        #pragma unroll
        for (int it = 0; it < 16; ++it) {
            const int u = it * 1024 + tid;      // (row, 16B-piece): 2048*8 units
            const int r = u >> 3, p = u & 7;
            float4 v = *(const float4*)(xw + (size_t)r * BATCH + p * 4);
            uint2 d;
            d.x = h22u(__floats2half2_rn(v.x, v.y));
            d.y = h22u(__floats2half2_rn(v.z, v.w));
            *(uint2*)(lds + r * 64 + p * 8) = d;
        }
    }

    // ---- phase 0b: T-walk for this block's 512 outputs ----
    if (tid < 512) {
        const int i = chunk * 512 + tid;
        int2 p3 = idx3[i];
        int n = 0;
        #pragma unroll
        for (int t = 0; t < 2; ++t) {
            int2 p2 = idx2[t ? p3.y : p3.x];
            #pragma unroll
            for (int u = 0; u < 2; ++u) {
                int2 p1 = idx1[u ? p2.y : p2.x];
                #pragma unroll
                for (int v = 0; v < 2; ++v) {
                    int2 p0 = idx0[v ? p1.y : p1.x];
                    unsigned wc = 0;
                    #pragma unroll
                    for (int e = 0; e < 2; ++e) {
                        int k = e ? p0.y : p0.x;
                        unsigned code;
                        if (k < 2) code = (unsigned)k << 11;
                        else       code = ((2u + (k & 1)) << 11) | ((unsigned)(k - 2) >> 1);
                        wc |= code << (16 * e);
                    }
                    Tl[tid * 8 + n] = wc;
                    ++n;
                }
            }
        }
    }
    __syncthreads();

    // ---- phase 1: compute (identical structure to R13) ----
    const int cg  = tid & 3;          // col group 0..3 (8 cols)
    const int ol  = tid >> 2;         // output-in-pass 0..255
    const int cgb = cg * 16;          // byte offset within 64-B row

    #pragma unroll 1
    for (int pass = 0; pass < 2; ++pass) {
        const int oloc = pass * 256 + ol;            // 0..511 within chunk
        const unsigned* tp = &Tl[oloc * 8];
        const unsigned tw[8] = {tp[0], tp[1], tp[2], tp[3],
                                tp[4], tp[5], tp[6], tp[7]};

        float accf[8];
        #pragma unroll
        for (int k = 0; k < 8; ++k) accf[k] = 0.f;

        #pragma unroll
        for (int a3 = 0; a3 < 2; ++a3) {                 // top SumLayer
            __half2 prod2[4];
            #pragma unroll
            for (int a2 = 0; a2 < 2; ++a2) {             // ProductLayer
                __half2 sum1[4];
                #pragma unroll
                for (int a1 = 0; a1 < 2; ++a1) {         // SumLayer
                    const int m = a3 * 4 + a2 * 2 + a1;
                    const unsigned wv = tw[m];
                    uint4 A = *(const uint4*)(lds + ((wv & 0x7FFu) << 6) + cgb);
                    uint4 B = *(const uint4*)(lds + (((wv >> 16) & 0x7FFu) << 6) + cgb);
                    unsigned sa, ca, sb, cb;
                    sel2sc((wv >> 11) & 3u, sa, ca);
                    sel2sc((wv >> 27) & 3u, sb, cb);
                    const unsigned aw[4] = {A.x, A.y, A.z, A.w};
                    const unsigned bw[4] = {B.x, B.y, B.z, B.w};
                    #pragma unroll
                    for (int k = 0; k < 4; ++k) {
                        __half2 va = __hfma2(u2h2(aw[k]), u2h2(sa), u2h2(ca));
                        __half2 vb = __hfma2(u2h2(bw[k]), u2h2(sb), u2h2(cb));
                        __half2 pr = __hmul2(va, vb);    // leaf product
                        sum1[k] = (a1 == 0) ? pr : __hadd2(sum1[k], pr);
                    }
                }
                #pragma unroll
                for (int k = 0; k < 4; ++k)
                    prod2[k] = (a2 == 0) ? sum1[k] : __hmul2(prod2[k], sum1[k]);
            }
            #pragma unroll
            for (int k = 0; k < 4; ++k) {                // top sum in f32
                float2 pf = __half22float2(prod2[k]);
                accf[2 * k]     += pf.x;
                accf[2 * k + 1] += pf.y;
            }
        }

        // lanes 4i..4i+3 cover cols w*32..w*32+31 = 128 B contiguous (full line)
        const int o = chunk * 512 + oloc;
        float* dst = out + (size_t)o * BATCH + w * 32 + cg * 8;
        f32x4 o0 = {accf[0], accf[1], accf[2], accf[3]};
        f32x4 o1 = {accf[4], accf[5], accf[6], accf[7]};
        __builtin_nontemporal_store(o0, reinterpret_cast<f32x4*>(dst));
        __builtin_nontemporal_store(o1, reinterpret_cast<f32x4*>(dst) + 1);
    }
}

extern "C" void kernel_launch(void* const* d_in, const int* in_sizes, int n_in,
                              void* d_out, int out_size, void* d_ws, size_t ws_size,
                              hipStream_t stream) {
    const float* x    = (const float*)d_in[0];
    const int2*  idx0 = (const int2*)d_in[1];
    const int2*  idx1 = (const int2*)d_in[2];
    const int2*  idx2 = (const int2*)d_in[3];
    const int2*  idx3 = (const int2*)d_in[4];
    float* out = (float*)d_out;

    knowledge_all<<<256, 1024, 0, stream>>>(x, idx0, idx1, idx2, idx3, out);
}

// Round 15
// 19.994 us; speedup vs baseline: 1.0324x; 1.0324x over previous
//
#include <hip/hip_runtime.h>
#include <hip/hip_fp16.h>

#define BATCH  1024
#define NVARS  2048
#define N_OUT  4096

#define W32BYTES (NVARS * 64)    // 128 KB per 32-col window (fp16, row = 64 B)
#define NW32     (BATCH / 32)    // 32 windows

typedef float f32x4 __attribute__((ext_vector_type(4)));
typedef unsigned u32x4 __attribute__((ext_vector_type(4)));

__device__ __forceinline__ __half2 u2h2(unsigned u) {
    union { unsigned u; __half2 h; } c; c.u = u; return c.h;
}
__device__ __forceinline__ unsigned h22u(__half2 h) {
    union { unsigned u; __half2 h; } c; c.h = h; return c.u;
}
__device__ __forceinline__ void sel2sc(unsigned sel, unsigned& s, unsigned& c) {
    // half2 constants: 1.0h2 = 0x3C003C00, -1.0h2 = 0xBC00BC00
    c = (sel & 1u) ? 0x3C003C00u : 0u;
    s = (sel == 2u) ? 0x3C003C00u : (sel == 3u) ? 0xBC00BC00u : 0u;
}

// ---------------- prep: LDS-tile transpose to 32-col-window fp16 + T-flatten ----
// xh2: [32 w][2048 r][32 cols fp16 = 64 B]; byte(w,r) = w*131072 + r*64
// T[i*8+m] = leafA | leafB<<16, leaf = sel<<11 | row. sel:0->0,1->1,2->x,3->1-x
// xh2/T stored NONTEMPORAL so no XCD's L2 holds them dirty: main's XCD-affine
// stage then pulls clean lines into its OWN L2.
__global__ __launch_bounds__(256) void prep_kernel(
    const float* __restrict__ x,
    const int2* __restrict__ idx0,
    const int2* __restrict__ idx1,
    const int2* __restrict__ idx2,
    const int2* __restrict__ idx3,
    unsigned* __restrict__ T,
    char* __restrict__ xh2)
{
    __shared__ char tile[64 * 272];    // 64 rows x 128 cols fp16, 272B padded rows

    const int bid = blockIdx.x;        // 256 blocks
    const int tid = threadIdx.x;
    const int rt  = bid >> 3;          // row tile 0..31
    const int ct  = bid & 7;           // col tile 0..7 (128 cols each)
    const int r0  = rt * 64;

    // ---- T-flatten on blocks 0..15 ----
    if (bid < 16) {
        const int i = bid * 256 + tid;
        int2 p3 = idx3[i];
        int n = 0;
        #pragma unroll
        for (int t = 0; t < 2; ++t) {
            int2 p2 = idx2[t ? p3.y : p3.x];
            #pragma unroll
            for (int u = 0; u < 2; ++u) {
                int2 p1 = idx1[u ? p2.y : p2.x];
                #pragma unroll
                for (int v = 0; v < 2; ++v) {
                    int2 p0 = idx0[v ? p1.y : p1.x];
                    unsigned w = 0;
                    #pragma unroll
                    for (int e = 0; e < 2; ++e) {
                        int k = e ? p0.y : p0.x;
                        unsigned code;
                        if (k < 2) code = (unsigned)k << 11;
                        else       code = ((2u + (k & 1)) << 11) | ((unsigned)(k - 2) >> 1);
                        w |= code << (16 * e);
                    }
                    __builtin_nontemporal_store(w, &T[(size_t)i * 8 + n]);
                    ++n;
                }
            }
        }
    }

    // ---- phase A: coalesced read of 64 rows x 128 cols, cvt fp16 into tile ----
    {
        const int r_l = tid >> 5;      // 0..7
        const int c4  = tid & 31;      // 0..31 float4 units
        #pragma unroll
        for (int q = 0; q < 8; ++q) {
            const int rr = q * 8 + r_l;                 // tile row 0..63
            float4 v = ((const float4*)x)[(size_t)(r0 + rr) * 256 + ct * 32 + c4];
            unsigned h0 = h22u(__floats2half2_rn(v.x, v.y));
            unsigned h1 = h22u(__floats2half2_rn(v.z, v.w));
            unsigned* p = (unsigned*)(tile + rr * 272 + c4 * 8);
            p[0] = h0; p[1] = h1;
        }
    }
    __syncthreads();

    // ---- phase B: write w32-major NT; per inst 64 lanes = 1 KB contiguous ----
    {
        const int wl = tid & 3;        // 16-B piece within 64-B row
        const int r2 = tid >> 2;       // 0..63
        #pragma unroll
        for (int g = 0; g < 4; ++g) {  // 32-col group within the 128-col tile
            u32x4 v = *reinterpret_cast<const u32x4*>(tile + r2 * 272 + g * 64 + wl * 16);
            const int w32 = ct * 4 + g;
            __builtin_nontemporal_store(
                v, reinterpret_cast<u32x4*>(
                       xh2 + (size_t)w32 * W32BYTES + (r0 + r2) * 64 + wl * 16));
        }
    }
}

// ---------------- main: 128 KiB LDS window, 1024 threads (16 waves/CU) --------
// 256 blocks x 1024 threads, 1 block/CU. XCD k (= bx&7) owns windows 4k..4k+3
// (all 8 chunk-blocks of a window share the XCD -> stage hits own L2 after
// first pull). Thread = (output ol, col-group cg of 8 cols); 2 passes.
// Lanes 4i..4i+3 store 128 B contiguous full lines; stores CACHED (out slice
// per XCD = 2 MB, fits its 4 MiB L2) so the HBM write drain leaves the
// kernel's critical path.
__global__ __launch_bounds__(1024) void knowledge_main(
    const char* __restrict__ xh2,
    const uint4* __restrict__ T4,     // 2 x uint4 per output (8 packed pair-words)
    float* __restrict__ out)
{
    __shared__ char lds[131072];      // the 32-col window: row r at byte r*64

    const int bx   = blockIdx.x;      // 256
    const int tid  = threadIdx.x;     // 0..1023
    const int xcd  = bx & 7;
    const int slot = bx >> 3;         // 0..31
    const int w    = xcd * 4 + (slot & 3);   // window 0..31 (cols w*32..)
    const int chunk= slot >> 2;       // 0..7 (512 outputs each)

    // ---- stage: linear 128 KiB copy (1 KB contiguous per wave-instr) ----
    {
        const char* src = xh2 + (size_t)w * W32BYTES;
        #pragma unroll
        for (int it = 0; it < 8; ++it) {
            const int u = it * 1024 + tid;         // 16-B unit 0..8191
            *(uint4*)(lds + u * 16) = *(const uint4*)(src + u * 16);
        }
    }
    __syncthreads();

    const int cg  = tid & 3;          // col group 0..3 (8 cols)
    const int ol  = tid >> 2;         // output-in-pass 0..255
    const int cgb = cg * 16;          // byte offset within 64-B row

    int o = chunk * 512 + ol;         // pass-0 output
    uint4 t0 = T4[(size_t)o * 2];
    uint4 t1 = T4[(size_t)o * 2 + 1];

    #pragma unroll 1
    for (int pass = 0; pass < 2; ++pass) {
        const unsigned tw[8] = {t0.x, t0.y, t0.z, t0.w, t1.x, t1.y, t1.z, t1.w};

        // prefetch next pass's T while this pass computes
        if (pass == 0) {
            t0 = T4[(size_t)(o + 256) * 2];
            t1 = T4[(size_t)(o + 256) * 2 + 1];
        }

        float accf[8];
        #pragma unroll
        for (int k = 0; k < 8; ++k) accf[k] = 0.f;

        #pragma unroll
        for (int a3 = 0; a3 < 2; ++a3) {                 // top SumLayer
            __half2 prod2[4];
            #pragma unroll
            for (int a2 = 0; a2 < 2; ++a2) {             // ProductLayer
                __half2 sum1[4];
                #pragma unroll
                for (int a1 = 0; a1 < 2; ++a1) {         // SumLayer
                    const int m = a3 * 4 + a2 * 2 + a1;
                    const unsigned wv = tw[m];
                    uint4 A = *(const uint4*)(lds + ((wv & 0x7FFu) << 6) + cgb);
                    uint4 B = *(const uint4*)(lds + (((wv >> 16) & 0x7FFu) << 6) + cgb);
                    unsigned sa, ca, sb, cb;
                    sel2sc((wv >> 11) & 3u, sa, ca);
                    sel2sc((wv >> 27) & 3u, sb, cb);
                    const unsigned aw[4] = {A.x, A.y, A.z, A.w};
                    const unsigned bw[4] = {B.x, B.y, B.z, B.w};
                    #pragma unroll
                    for (int k = 0; k < 4; ++k) {
                        __half2 va = __hfma2(u2h2(aw[k]), u2h2(sa), u2h2(ca));
                        __half2 vb = __hfma2(u2h2(bw[k]), u2h2(sb), u2h2(cb));
                        __half2 pr = __hmul2(va, vb);    // leaf product
                        sum1[k] = (a1 == 0) ? pr : __hadd2(sum1[k], pr);
                    }
                }
                #pragma unroll
                for (int k = 0; k < 4; ++k)
                    prod2[k] = (a2 == 0) ? sum1[k] : __hmul2(prod2[k], sum1[k]);
            }
            #pragma unroll
            for (int k = 0; k < 4; ++k) {                // top sum in f32
                float2 pf = __half22float2(prod2[k]);
                accf[2 * k]     += pf.x;
                accf[2 * k + 1] += pf.y;
            }
        }

        // lanes 4i..4i+3 cover cols w*32..w*32+31 = 128 B contiguous (full line)
        float* dst = out + (size_t)o * BATCH + w * 32 + cg * 8;
        f32x4 o0 = {accf[0], accf[1], accf[2], accf[3]};
        f32x4 o1 = {accf[4], accf[5], accf[6], accf[7]};
        *reinterpret_cast<f32x4*>(dst)     = o0;      // cached write-back
        *(reinterpret_cast<f32x4*>(dst) + 1) = o1;

        o += 256;
    }
}

// ---------------- fallback (round-1 kernel) if ws too small ----------------
__device__ __forceinline__ float Hval(int k, const float* __restrict__ x, int b) {
    if (k < 2) return (float)k;
    float v = x[((k - 2) >> 1) * BATCH + b];
    return (k & 1) ? 1.0f - v : v;
}

__global__ __launch_bounds__(256) void knowledge_fused_kernel(
    const float* __restrict__ x,
    const int2* __restrict__ idx0,
    const int2* __restrict__ idx1,
    const int2* __restrict__ idx2,
    const int2* __restrict__ idx3,
    float* __restrict__ out)
{
    const int i = blockIdx.x;
    const int b = blockIdx.y * blockDim.x + threadIdx.x;
    const int2 p3 = idx3[i];
    float acc3 = 0.0f;
    #pragma unroll
    for (int t = 0; t < 2; ++t) {
        const int2 p2 = idx2[t ? p3.y : p3.x];
        float prod2 = 1.0f;
        #pragma unroll
        for (int u = 0; u < 2; ++u) {
            const int2 p1 = idx1[u ? p2.y : p2.x];
            float sum1 = 0.0f;
            #pragma unroll
            for (int v = 0; v < 2; ++v) {
                const int2 p0 = idx0[v ? p1.y : p1.x];
                sum1 += Hval(p0.x, x, b) * Hval(p0.y, x, b);
            }
            prod2 *= sum1;
        }
        acc3 += prod2;
    }
    out[(size_t)i * BATCH + b] = acc3;
}

extern "C" void kernel_launch(void* const* d_in, const int* in_sizes, int n_in,
                              void* d_out, int out_size, void* d_ws, size_t ws_size,
                              hipStream_t stream) {
    const float* x    = (const float*)d_in[0];
    const int2*  idx0 = (const int2*)d_in[1];
    const int2*  idx1 = (const int2*)d_in[2];
    const int2*  idx2 = (const int2*)d_in[3];
    const int2*  idx3 = (const int2*)d_in[4];
    float* out = (float*)d_out;

    const size_t t_bytes   = (size_t)N_OUT * 8 * sizeof(unsigned);   // 128 KB
    const size_t xh2_bytes = (size_t)NW32 * W32BYTES;                // 4 MB
    if (ws_size >= t_bytes + xh2_bytes) {
        unsigned* T   = (unsigned*)d_ws;
        char*     xh2 = (char*)d_ws + t_bytes;
        prep_kernel<<<256, 256, 0, stream>>>(x, idx0, idx1, idx2, idx3, T, xh2);
        knowledge_main<<<256, 1024, 0, stream>>>(xh2, (const uint4*)T, out);
    } else {
        dim3 grid(N_OUT, BATCH / 256);
        knowledge_fused_kernel<<<grid, 256, 0, stream>>>(x, idx0, idx1, idx2, idx3, out);
    }
}

// Round 16
// 19.949 us; speedup vs baseline: 1.0348x; 1.0023x over previous
//
#include <hip/hip_runtime.h>
#include <hip/hip_fp16.h>

#define BATCH  1024
#define NVARS  2048
#define N_OUT  4096

typedef float f32x4 __attribute__((ext_vector_type(4)));

__device__ __forceinline__ __half2 u2h2(unsigned u) {
    union { unsigned u; __half2 h; } c; c.u = u; return c.h;
}
__device__ __forceinline__ unsigned h22u(__half2 h) {
    union { unsigned u; __half2 h; } c; c.h = h; return c.u;
}
__device__ __forceinline__ void sel2sc(unsigned sel, unsigned& s, unsigned& c) {
    // half2 constants: 1.0h2 = 0x3C003C00, -1.0h2 = 0xBC00BC00
    c = (sel & 1u) ? 0x3C003C00u : 0u;
    s = (sel == 2u) ? 0x3C003C00u : (sel == 3u) ? 0xBC00BC00u : 0u;
}

// ---------------- kernel 1: T-flatten ONLY (once, deduplicated) ----------------
// T[i*8+m] = leafA | leafB<<16, leaf = sel<<11 | row. sel:0->0,1->1,2->x,3->1-x
__global__ __launch_bounds__(256) void tflat_kernel(
    const int2* __restrict__ idx0,
    const int2* __restrict__ idx1,
    const int2* __restrict__ idx2,
    const int2* __restrict__ idx3,
    unsigned* __restrict__ T)
{
    const int i = blockIdx.x * 256 + threadIdx.x;   // 16 blocks x 256 = 4096
    int2 p3 = idx3[i];
    int n = 0;
    #pragma unroll
    for (int t = 0; t < 2; ++t) {
        int2 p2 = idx2[t ? p3.y : p3.x];
        #pragma unroll
        for (int u = 0; u < 2; ++u) {
            int2 p1 = idx1[u ? p2.y : p2.x];
            #pragma unroll
            for (int v = 0; v < 2; ++v) {
                int2 p0 = idx0[v ? p1.y : p1.x];
                unsigned w = 0;
                #pragma unroll
                for (int e = 0; e < 2; ++e) {
                    int k = e ? p0.y : p0.x;
                    unsigned code;
                    if (k < 2) code = (unsigned)k << 11;
                    else       code = ((2u + (k & 1)) << 11) | ((unsigned)(k - 2) >> 1);
                    w |= code << (16 * e);
                }
                __builtin_nontemporal_store(w, &T[(size_t)i * 8 + n]);
                ++n;
            }
        }
    }
}

// ---------------- kernel 2: fused stage(x->LDS fp16) + compute + NT store -------
// 256 blocks x 1024 threads, 1 block/CU (128 KiB LDS). XCD k (= bx&7) owns
// windows 4k..4k+3; the 8 chunk-blocks of a window share the XCD -> the x
// window slice (2048 x 128 B lines, 1 MB/XCD) is L2-resident with 8x reuse.
// Stage: f32 full-line reads, fp16 cvt in flight (no xh2 round-trip).
// Compute: R13-proven 2 passes x 256 outputs, 16 ds_read_b128 per output,
// fp16 tree, f32 top sum. Stores: full-line NT pairs (R15 showed NT > cached).
__global__ __launch_bounds__(1024) void knowledge_main(
    const float* __restrict__ x,
    const uint4* __restrict__ T4,     // 2 x uint4 per output (8 packed pair-words)
    float* __restrict__ out)
{
    __shared__ char lds[131072];      // window: row r at byte r*64 (32 fp16 cols)

    const int bx    = blockIdx.x;     // 256
    const int tid   = threadIdx.x;    // 0..1023
    const int xcd   = bx & 7;
    const int slot  = bx >> 3;        // 0..31
    const int w     = xcd * 4 + (slot & 3);  // window 0..31 (cols w*32..w*32+31)
    const int chunk = slot >> 2;      // 0..7 (512 outputs each)

    // ---- stage: x slice (2048 rows x 32 f32) -> LDS fp16, full-line reads ----
    {
        const float4* x4 = (const float4*)x;   // row stride 256 float4
        #pragma unroll
        for (int it = 0; it < 16; ++it) {
            const int u = it * 1024 + tid;     // (row, 16B-piece): 2048*8 units
            const int r = u >> 3, p = u & 7;
            float4 v = x4[(size_t)r * 256 + w * 8 + p];
            uint2 d;
            d.x = h22u(__floats2half2_rn(v.x, v.y));
            d.y = h22u(__floats2half2_rn(v.z, v.w));
            *(uint2*)(lds + r * 64 + p * 8) = d;
        }
    }
    __syncthreads();

    const int cg  = tid & 3;          // col group 0..3 (8 cols)
    const int ol  = tid >> 2;         // output-in-pass 0..255
    const int cgb = cg * 16;          // byte offset within 64-B row

    int o = chunk * 512 + ol;         // pass-0 output
    uint4 t0 = T4[(size_t)o * 2];
    uint4 t1 = T4[(size_t)o * 2 + 1];

    #pragma unroll 1
    for (int pass = 0; pass < 2; ++pass) {
        const unsigned tw[8] = {t0.x, t0.y, t0.z, t0.w, t1.x, t1.y, t1.z, t1.w};

        // prefetch next pass's T while this pass computes
        if (pass == 0) {
            t0 = T4[(size_t)(o + 256) * 2];
            t1 = T4[(size_t)(o + 256) * 2 + 1];
        }

        float accf[8];
        #pragma unroll
        for (int k = 0; k < 8; ++k) accf[k] = 0.f;

        #pragma unroll
        for (int a3 = 0; a3 < 2; ++a3) {                 // top SumLayer
            __half2 prod2[4];
            #pragma unroll
            for (int a2 = 0; a2 < 2; ++a2) {             // ProductLayer
                __half2 sum1[4];
                #pragma unroll
                for (int a1 = 0; a1 < 2; ++a1) {         // SumLayer
                    const int m = a3 * 4 + a2 * 2 + a1;
                    const unsigned wv = tw[m];
                    uint4 A = *(const uint4*)(lds + ((wv & 0x7FFu) << 6) + cgb);
                    uint4 B = *(const uint4*)(lds + (((wv >> 16) & 0x7FFu) << 6) + cgb);
                    unsigned sa, ca, sb, cb;
                    sel2sc((wv >> 11) & 3u, sa, ca);
                    sel2sc((wv >> 27) & 3u, sb, cb);
                    const unsigned aw[4] = {A.x, A.y, A.z, A.w};
                    const unsigned bw[4] = {B.x, B.y, B.z, B.w};
                    #pragma unroll
                    for (int k = 0; k < 4; ++k) {
                        __half2 va = __hfma2(u2h2(aw[k]), u2h2(sa), u2h2(ca));
                        __half2 vb = __hfma2(u2h2(bw[k]), u2h2(sb), u2h2(cb));
                        __half2 pr = __hmul2(va, vb);    // leaf product
                        sum1[k] = (a1 == 0) ? pr : __hadd2(sum1[k], pr);
                    }
                }
                #pragma unroll
                for (int k = 0; k < 4; ++k)
                    prod2[k] = (a2 == 0) ? sum1[k] : __hmul2(prod2[k], sum1[k]);
            }
            #pragma unroll
            for (int k = 0; k < 4; ++k) {                // top sum in f32
                float2 pf = __half22float2(prod2[k]);
                accf[2 * k]     += pf.x;
                accf[2 * k + 1] += pf.y;
            }
        }

        // lanes 4i..4i+3 cover cols w*32..w*32+31 = 128 B contiguous (full line)
        float* dst = out + (size_t)o * BATCH + w * 32 + cg * 8;
        f32x4 o0 = {accf[0], accf[1], accf[2], accf[3]};
        f32x4 o1 = {accf[4], accf[5], accf[6], accf[7]};
        __builtin_nontemporal_store(o0, reinterpret_cast<f32x4*>(dst));
        __builtin_nontemporal_store(o1, reinterpret_cast<f32x4*>(dst) + 1);

        o += 256;
    }
}

// ---------------- fallback (round-1 kernel) if ws too small ----------------
__device__ __forceinline__ float Hval(int k, const float* __restrict__ x, int b) {
    if (k < 2) return (float)k;
    float v = x[((k - 2) >> 1) * BATCH + b];
    return (k & 1) ? 1.0f - v : v;
}

__global__ __launch_bounds__(256) void knowledge_fused_kernel(
    const float* __restrict__ x,
    const int2* __restrict__ idx0,
    const int2* __restrict__ idx1,
    const int2* __restrict__ idx2,
    const int2* __restrict__ idx3,
    float* __restrict__ out)
{
    const int i = blockIdx.x;
    const int b = blockIdx.y * blockDim.x + threadIdx.x;
    const int2 p3 = idx3[i];
    float acc3 = 0.0f;
    #pragma unroll
    for (int t = 0; t < 2; ++t) {
        const int2 p2 = idx2[t ? p3.y : p3.x];
        float prod2 = 1.0f;
        #pragma unroll
        for (int u = 0; u < 2; ++u) {
            const int2 p1 = idx1[u ? p2.y : p2.x];
            float sum1 = 0.0f;
            #pragma unroll
            for (int v = 0; v < 2; ++v) {
                const int2 p0 = idx0[v ? p1.y : p1.x];
                sum1 += Hval(p0.x, x, b) * Hval(p0.y, x, b);
            }
            prod2 *= sum1;
        }
        acc3 += prod2;
    }
    out[(size_t)i * BATCH + b] = acc3;
}

extern "C" void kernel_launch(void* const* d_in, const int* in_sizes, int n_in,
                              void* d_out, int out_size, void* d_ws, size_t ws_size,
                              hipStream_t stream) {
    const float* x    = (const float*)d_in[0];
    const int2*  idx0 = (const int2*)d_in[1];
    const int2*  idx1 = (const int2*)d_in[2];
    const int2*  idx2 = (const int2*)d_in[3];
    const int2*  idx3 = (const int2*)d_in[4];
    float* out = (float*)d_out;

    const size_t t_bytes = (size_t)N_OUT * 8 * sizeof(unsigned);   // 128 KB
    if (ws_size >= t_bytes) {
        unsigned* T = (unsigned*)d_ws;
        tflat_kernel<<<16, 256, 0, stream>>>(idx0, idx1, idx2, idx3, T);
        knowledge_main<<<256, 1024, 0, stream>>>(x, (const uint4*)T, out);
    } else {
        dim3 grid(N_OUT, BATCH / 256);
        knowledge_fused_kernel<<<grid, 256, 0, stream>>>(x, idx0, idx1, idx2, idx3, out);
    }
}